// Round 1
// baseline (827.598 us; speedup 1.0000x reference)
//
#include <hip/hip_runtime.h>
#include <math.h>

#define BB 32
#define NN 96
#define DD 32
#define FF 16
#define NE (NN * NN)          // 9216 edges per batch
#define PAIRS (BB * NN)       // 3072 (b,i) pairs
#define PPB 6                 // pairs per block (96 % 6 == 0 -> same b within block)
#define GRID_A (PAIRS / PPB)  // 512 blocks = 2 per CU

// ---------------------------------------------------------------------------
// Kernel A: fused  A=relu(edges@W+b) ; msg = A·nodes[j] ; agg = sum_j mask*msg
// Lane mapping: lane l owns k = l + 64*t (t=0..15)  ->  q = l&31, p = 2t+(l>>5)
//   * W LDS read  Wl[f*1024 + l + 64t]: bank = l&31 -> 2-way alias = free
//   * message contraction is lane-private (same q for all 16 k's)
//   * one cross-lane reduce per (b,i) pair, not per edge
// Mask==0 edges skipped exactly (mask is exactly 0.0/1.0).
// ---------------------------------------------------------------------------
__global__ __launch_bounds__(256, 2)
void agg_kernel(const float* __restrict__ nodes, const float* __restrict__ edges,
                const float* __restrict__ mask, const float* __restrict__ W_agg,
                const float* __restrict__ b_agg, float* __restrict__ agg_out) {
    __shared__ __align__(16) float Wl[FF * 1024];   // 64 KB
    __shared__ __align__(16) float nodl[NN * DD];   // 12 KB
    __shared__ int jlist[NN];
    __shared__ int jcnt;
    __shared__ float aggl[DD];

    const int tid  = threadIdx.x;
    const int lane = tid & 63;
    const int wv   = tid >> 6;
    const int pair0 = blockIdx.x * PPB;
    const int b  = pair0 / NN;
    const int i0 = pair0 % NN;

    // stage W_agg (16x1024 f32) linearly: 4096 float4 / 256 threads = 16 each
    #pragma unroll
    for (int c = 0; c < 16; ++c) {
        int v = c * 256 + tid;
        ((float4*)Wl)[v] = ((const float4*)W_agg)[v];
    }
    // stage nodes[b]: 3072 floats = 768 float4
    #pragma unroll
    for (int c = 0; c < 3; ++c) {
        int v = c * 256 + tid;
        ((float4*)nodl)[v] = ((const float4*)(nodes + b * NN * DD))[v];
    }
    // per-lane bias values for k = lane + 64t
    float bv[16];
    #pragma unroll
    for (int t = 0; t < 16; ++t) bv[t] = b_agg[lane + 64 * t];

    for (int pp = 0; pp < PPB; ++pp) {
        const int i = i0 + pp;
        __syncthreads();                 // protect jlist/aggl from prev iter
        if (tid == 0) jcnt = 0;
        if (tid < DD) aggl[tid] = 0.f;
        __syncthreads();
        // compact unmasked edge list (order irrelevant for the sum)
        if (tid < NN) {
            float m = mask[b * NE + i * NN + tid];
            if (m != 0.f) { int p = atomicAdd(&jcnt, 1); jlist[p] = tid; }
        }
        __syncthreads();
        const int cnt = jcnt;
        const int ngroups = (cnt + 3) >> 2;

        float aggacc[16];
        #pragma unroll
        for (int t = 0; t < 16; ++t) aggacc[t] = 0.f;

        for (int g = wv; g < ngroups; g += 4) {
            const int e0 = g * 4;
            int jj[4];
            float evf[4][16];
            #pragma unroll
            for (int e = 0; e < 4; ++e) {
                int idx = e0 + e;
                int j = (idx < cnt) ? jlist[idx] : -1;
                jj[e] = j;
                const float4* ep = (const float4*)(edges +
                    ((size_t)b * NE + (size_t)i * NN + (j < 0 ? 0 : j)) * FF);
                #pragma unroll
                for (int u = 0; u < 4; ++u) {
                    float4 t4 = ep[u];
                    evf[e][4*u+0] = t4.x; evf[e][4*u+1] = t4.y;
                    evf[e][4*u+2] = t4.z; evf[e][4*u+3] = t4.w;
                }
            }
            float acc[4][16];
            #pragma unroll
            for (int e = 0; e < 4; ++e)
                #pragma unroll
                for (int t = 0; t < 16; ++t) acc[e][t] = bv[t];
            // main FMA loop: 256 LDS reads + 1024 FMAs per 4-edge group
            #pragma unroll
            for (int f = 0; f < FF; ++f) {
                float wvv[16];
                #pragma unroll
                for (int t = 0; t < 16; ++t)
                    wvv[t] = Wl[f * 1024 + lane + 64 * t];
                #pragma unroll
                for (int e = 0; e < 4; ++e) {
                    float ef = evf[e][f];
                    #pragma unroll
                    for (int t = 0; t < 16; ++t)
                        acc[e][t] = fmaf(ef, wvv[t], acc[e][t]);
                }
            }
            // epilogue: relu, multiply by nodes[j][q], accumulate (lane-private)
            #pragma unroll
            for (int e = 0; e < 4; ++e) {
                if (jj[e] >= 0) {
                    float nv = nodl[jj[e] * DD + (lane & 31)];
                    #pragma unroll
                    for (int t = 0; t < 16; ++t)
                        aggacc[t] = fmaf(fmaxf(acc[e][t], 0.f), nv, aggacc[t]);
                }
            }
        }
        // q-reduction: butterfly within each 32-lane half (p = 2t + half)
        #pragma unroll
        for (int off = 16; off >= 1; off >>= 1) {
            #pragma unroll
            for (int t = 0; t < 16; ++t)
                aggacc[t] += __shfl_xor(aggacc[t], off, 64);
        }
        if ((lane & 31) == 0) {
            int half = lane >> 5;
            #pragma unroll
            for (int t = 0; t < 16; ++t)
                atomicAdd(&aggl[2 * t + half], aggacc[t]);
        }
        __syncthreads();
        if (tid < DD) agg_out[(size_t)(pair0 + pp) * DD + tid] = aggl[tid];
    }
}

// ---------------------------------------------------------------------------
// Kernel B: GRU combiner. h1 = cell(h=0, nodes); h2 = cell(h1, agg). Out = h2.
// thread = (row, d); 8 rows per 256-thread block; weights staged padded [96][36].
// ---------------------------------------------------------------------------
__device__ __forceinline__ float dot32(const float* __restrict__ x,
                                       const float* __restrict__ w) {
    float s = 0.f;
    #pragma unroll
    for (int u = 0; u < 8; ++u) {
        float4 a = *(const float4*)(x + 4 * u);
        float4 c = *(const float4*)(w + 4 * u);
        s = fmaf(a.x, c.x, fmaf(a.y, c.y, fmaf(a.z, c.z, fmaf(a.w, c.w, s))));
    }
    return s;
}
__device__ __forceinline__ float sigm(float x) { return 1.f / (1.f + expf(-x)); }

__global__ __launch_bounds__(256, 4)
void gru_kernel(const float* __restrict__ nodes, const float* __restrict__ agg,
                const float* __restrict__ w_ih, const float* __restrict__ w_hh,
                const float* __restrict__ b_ih, const float* __restrict__ b_hh,
                float* __restrict__ out) {
    __shared__ __align__(16) float wih[96 * 36];
    __shared__ __align__(16) float whh[96 * 36];
    __shared__ float bihs[96], bhhs[96];
    __shared__ __align__(16) float xs[8][32], as_[8][32], h1s[8][32];

    const int tid = threadIdx.x;
    // stage weights with +4 row padding (16B-aligned rows, spread banks)
    for (int v = tid; v < 768; v += 256) {
        int row = v >> 3, c4 = v & 7;
        *(float4*)&wih[row * 36 + c4 * 4] = ((const float4*)w_ih)[v];
        *(float4*)&whh[row * 36 + c4 * 4] = ((const float4*)w_hh)[v];
    }
    if (tid < 96) { bihs[tid] = b_ih[tid]; bhhs[tid] = b_hh[tid]; }

    const int rl = tid >> 5, d = tid & 31;
    const int row = blockIdx.x * 8 + rl;
    xs[rl][d]  = nodes[row * 32 + d];
    as_[rl][d] = agg[row * 32 + d];
    __syncthreads();

    // cell 1: h = 0  ->  gh = b_hh exactly
    float gi_r = dot32(&xs[rl][0], &wih[(0 * 32 + d) * 36]) + bihs[0 * 32 + d];
    float gi_z = dot32(&xs[rl][0], &wih[(1 * 32 + d) * 36]) + bihs[1 * 32 + d];
    float gi_n = dot32(&xs[rl][0], &wih[(2 * 32 + d) * 36]) + bihs[2 * 32 + d];
    float r1 = sigm(gi_r + bhhs[0 * 32 + d]);
    float z1 = sigm(gi_z + bhhs[1 * 32 + d]);
    float n1 = tanhf(gi_n + r1 * bhhs[2 * 32 + d]);
    float h1 = (1.f - z1) * n1;
    h1s[rl][d] = h1;
    __syncthreads();

    // cell 2: x = agg, h = h1
    float gi2_r = dot32(&as_[rl][0], &wih[(0 * 32 + d) * 36]) + bihs[0 * 32 + d];
    float gi2_z = dot32(&as_[rl][0], &wih[(1 * 32 + d) * 36]) + bihs[1 * 32 + d];
    float gi2_n = dot32(&as_[rl][0], &wih[(2 * 32 + d) * 36]) + bihs[2 * 32 + d];
    float gh2_r = dot32(&h1s[rl][0], &whh[(0 * 32 + d) * 36]) + bhhs[0 * 32 + d];
    float gh2_z = dot32(&h1s[rl][0], &whh[(1 * 32 + d) * 36]) + bhhs[1 * 32 + d];
    float gh2_n = dot32(&h1s[rl][0], &whh[(2 * 32 + d) * 36]) + bhhs[2 * 32 + d];
    float r2 = sigm(gi2_r + gh2_r);
    float z2 = sigm(gi2_z + gh2_z);
    float n2 = tanhf(gi2_n + r2 * gh2_n);
    float h2 = (1.f - z2) * n2 + z2 * h1;
    out[row * 32 + d] = h2;
}

extern "C" void kernel_launch(void* const* d_in, const int* in_sizes, int n_in,
                              void* d_out, int out_size, void* d_ws, size_t ws_size,
                              hipStream_t stream) {
    const float* nodes = (const float*)d_in[0];
    const float* edges = (const float*)d_in[1];
    const float* mask  = (const float*)d_in[2];
    const float* W_agg = (const float*)d_in[3];
    const float* b_agg = (const float*)d_in[4];
    const float* w_ih  = (const float*)d_in[5];
    const float* w_hh  = (const float*)d_in[6];
    const float* b_ih  = (const float*)d_in[7];
    const float* b_hh  = (const float*)d_in[8];
    float* out = (float*)d_out;
    float* agg = (float*)d_ws;   // 3072*32*4 = 384 KB scratch

    agg_kernel<<<GRID_A, 256, 0, stream>>>(nodes, edges, mask, W_agg, b_agg, agg);
    gru_kernel<<<PAIRS / 8, 256, 0, stream>>>(nodes, agg, w_ih, w_hh, b_ih, b_hh, out);
}

// Round 2
// 784.147 us; speedup vs baseline: 1.0554x; 1.0554x over previous
//
#include <hip/hip_runtime.h>
#include <math.h>

#define BB 32
#define NN 96
#define DD 32
#define FF 16
#define NE (NN * NN)          // 9216 edges per batch
#define PAIRS (BB * NN)       // 3072 (b,i) pairs
#define PPB 6                 // pairs per block (96 % 6 == 0 -> same b within block)
#define GRID_A (PAIRS / PPB)  // 512 blocks = 2 per CU

// ---------------------------------------------------------------------------
// Kernel A: fused  A=relu(edges@W+b) ; msg = A·nodes[j] ; agg = sum_j mask*msg
// Lane/wave mapping (spill-free rewrite):
//   8 waves/block. Wave wv: t-half = wv>>2 (owns t = 8*thalf .. +8),
//   edge-group parity = wv&3 (groups strided by 4 within the t-half).
//   Lane l owns k = l + 64*t  ->  q = l&31, p = 2t + (l>>5).
//   * W LDS read Wl[f*1024 + l + 64t]: bank = l&31 -> 2-way alias = free
//   * per-wave live set: acc[4][8]+ev[4]+wvv[8]+aggacc[8]+bv[8] ~= 95 VGPR
//     (round-1 version held ~190 floats -> spilled 1.5 GB of scratch traffic)
// Mask==0 edges skipped exactly (mask is exactly 0.0/1.0).
// ---------------------------------------------------------------------------
__global__ __launch_bounds__(512, 4)
void agg_kernel(const float* __restrict__ nodes, const float* __restrict__ edges,
                const float* __restrict__ mask, const float* __restrict__ W_agg,
                const float* __restrict__ b_agg, float* __restrict__ agg_out) {
    __shared__ __align__(16) float Wl[FF * 1024];   // 64 KB
    __shared__ __align__(16) float nodl[NN * DD];   // 12 KB
    __shared__ int jlist[NN];
    __shared__ int jcnt;
    __shared__ float aggl[DD];

    const int tid   = threadIdx.x;
    const int lane  = tid & 63;
    const int wv    = tid >> 6;       // 0..7
    const int thalf = wv >> 2;        // 0..1 -> which 8 t's this wave owns
    const int gpar  = wv & 3;         // edge-group parity within the t-half
    const int t0    = thalf * 8;
    const int pair0 = blockIdx.x * PPB;
    const int b  = pair0 / NN;
    const int i0 = pair0 % NN;

    // stage W_agg (16x1024 f32 = 4096 float4) linearly: 8 per thread
    #pragma unroll
    for (int c = 0; c < 8; ++c) {
        int v = c * 512 + tid;
        ((float4*)Wl)[v] = ((const float4*)W_agg)[v];
    }
    // stage nodes[b]: 768 float4
    for (int v = tid; v < 768; v += 512)
        ((float4*)nodl)[v] = ((const float4*)(nodes + b * NN * DD))[v];

    // per-lane bias for this wave's 8 k-slots (k = lane + 64t)
    float bv[8];
    #pragma unroll
    for (int t2 = 0; t2 < 8; ++t2) bv[t2] = b_agg[lane + 64 * (t0 + t2)];

    for (int pp = 0; pp < PPB; ++pp) {
        const int i = i0 + pp;
        __syncthreads();                 // protect jlist/aggl from prev iter
        if (tid == 0) jcnt = 0;
        if (tid < DD) aggl[tid] = 0.f;
        __syncthreads();
        // compact unmasked edge list (order irrelevant for the sum)
        if (tid < NN) {
            if (mask[b * NE + i * NN + tid] != 0.f) {
                int p = atomicAdd(&jcnt, 1);
                jlist[p] = tid;
            }
        }
        __syncthreads();
        const int cnt = jcnt;
        const int ngroups = (cnt + 3) >> 2;

        float aggacc[8];
        #pragma unroll
        for (int t2 = 0; t2 < 8; ++t2) aggacc[t2] = 0.f;

        const float* ebase = edges + ((size_t)b * NE + (size_t)i * NN) * FF;

        for (int g = gpar; g < ngroups; g += 4) {
            const int e0 = g * 4;
            int jj[4], jc[4];
            #pragma unroll
            for (int e = 0; e < 4; ++e) {
                jj[e] = (e0 + e < cnt) ? jlist[e0 + e] : -1;
                jc[e] = (jj[e] < 0) ? 0 : jj[e];
            }
            float acc[4][8];
            #pragma unroll
            for (int e = 0; e < 4; ++e)
                #pragma unroll
                for (int t2 = 0; t2 < 8; ++t2) acc[e][t2] = bv[t2];
            // stream edge features in float4 chunks; f ascending (matches ref order)
            #pragma unroll
            for (int u = 0; u < 4; ++u) {
                float4 ev[4];
                #pragma unroll
                for (int e = 0; e < 4; ++e)
                    ev[e] = *(const float4*)(ebase + jc[e] * FF + 4 * u);
                #pragma unroll
                for (int f2 = 0; f2 < 4; ++f2) {
                    float wvv[8];
                    #pragma unroll
                    for (int t2 = 0; t2 < 8; ++t2)
                        wvv[t2] = Wl[(4 * u + f2) * 1024 + lane + 64 * (t0 + t2)];
                    #pragma unroll
                    for (int e = 0; e < 4; ++e) {
                        const float ef = (f2 == 0) ? ev[e].x : (f2 == 1) ? ev[e].y
                                       : (f2 == 2) ? ev[e].z : ev[e].w;
                        #pragma unroll
                        for (int t2 = 0; t2 < 8; ++t2)
                            acc[e][t2] = fmaf(ef, wvv[t2], acc[e][t2]);
                    }
                }
            }
            // epilogue: relu, multiply by nodes[j][q], accumulate (lane-private)
            #pragma unroll
            for (int e = 0; e < 4; ++e) {
                if (jj[e] >= 0) {
                    float nv = nodl[jj[e] * DD + (lane & 31)];
                    #pragma unroll
                    for (int t2 = 0; t2 < 8; ++t2)
                        aggacc[t2] = fmaf(fmaxf(acc[e][t2], 0.f), nv, aggacc[t2]);
                }
            }
        }
        // q-reduction: butterfly within each 32-lane half (p = 2t + half)
        #pragma unroll
        for (int off = 16; off >= 1; off >>= 1) {
            #pragma unroll
            for (int t2 = 0; t2 < 8; ++t2)
                aggacc[t2] += __shfl_xor(aggacc[t2], off, 64);
        }
        if ((lane & 31) == 0) {
            const int half = lane >> 5;
            #pragma unroll
            for (int t2 = 0; t2 < 8; ++t2)
                atomicAdd(&aggl[2 * (t0 + t2) + half], aggacc[t2]);
        }
        __syncthreads();
        if (tid < DD) agg_out[(size_t)(pair0 + pp) * DD + tid] = aggl[tid];
    }
}

// ---------------------------------------------------------------------------
// Kernel B: GRU combiner. h1 = cell(h=0, nodes); h2 = cell(h1, agg). Out = h2.
// thread = (row, d); 8 rows per 256-thread block; weights staged padded [96][36].
// ---------------------------------------------------------------------------
__device__ __forceinline__ float dot32(const float* __restrict__ x,
                                       const float* __restrict__ w) {
    float s = 0.f;
    #pragma unroll
    for (int u = 0; u < 8; ++u) {
        float4 a = *(const float4*)(x + 4 * u);
        float4 c = *(const float4*)(w + 4 * u);
        s = fmaf(a.x, c.x, fmaf(a.y, c.y, fmaf(a.z, c.z, fmaf(a.w, c.w, s))));
    }
    return s;
}
__device__ __forceinline__ float sigm(float x) { return 1.f / (1.f + expf(-x)); }

__global__ __launch_bounds__(256, 4)
void gru_kernel(const float* __restrict__ nodes, const float* __restrict__ agg,
                const float* __restrict__ w_ih, const float* __restrict__ w_hh,
                const float* __restrict__ b_ih, const float* __restrict__ b_hh,
                float* __restrict__ out) {
    __shared__ __align__(16) float wih[96 * 36];
    __shared__ __align__(16) float whh[96 * 36];
    __shared__ float bihs[96], bhhs[96];
    __shared__ __align__(16) float xs[8][32], as_[8][32], h1s[8][32];

    const int tid = threadIdx.x;
    // stage weights with +4 row padding (16B-aligned rows, spread banks)
    for (int v = tid; v < 768; v += 256) {
        int row = v >> 3, c4 = v & 7;
        *(float4*)&wih[row * 36 + c4 * 4] = ((const float4*)w_ih)[v];
        *(float4*)&whh[row * 36 + c4 * 4] = ((const float4*)w_hh)[v];
    }
    if (tid < 96) { bihs[tid] = b_ih[tid]; bhhs[tid] = b_hh[tid]; }

    const int rl = tid >> 5, d = tid & 31;
    const int row = blockIdx.x * 8 + rl;
    xs[rl][d]  = nodes[row * 32 + d];
    as_[rl][d] = agg[row * 32 + d];
    __syncthreads();

    // cell 1: h = 0  ->  gh = b_hh exactly
    float gi_r = dot32(&xs[rl][0], &wih[(0 * 32 + d) * 36]) + bihs[0 * 32 + d];
    float gi_z = dot32(&xs[rl][0], &wih[(1 * 32 + d) * 36]) + bihs[1 * 32 + d];
    float gi_n = dot32(&xs[rl][0], &wih[(2 * 32 + d) * 36]) + bihs[2 * 32 + d];
    float r1 = sigm(gi_r + bhhs[0 * 32 + d]);
    float z1 = sigm(gi_z + bhhs[1 * 32 + d]);
    float n1 = tanhf(gi_n + r1 * bhhs[2 * 32 + d]);
    float h1 = (1.f - z1) * n1;
    h1s[rl][d] = h1;
    __syncthreads();

    // cell 2: x = agg, h = h1
    float gi2_r = dot32(&as_[rl][0], &wih[(0 * 32 + d) * 36]) + bihs[0 * 32 + d];
    float gi2_z = dot32(&as_[rl][0], &wih[(1 * 32 + d) * 36]) + bihs[1 * 32 + d];
    float gi2_n = dot32(&as_[rl][0], &wih[(2 * 32 + d) * 36]) + bihs[2 * 32 + d];
    float gh2_r = dot32(&h1s[rl][0], &whh[(0 * 32 + d) * 36]) + bhhs[0 * 32 + d];
    float gh2_z = dot32(&h1s[rl][0], &whh[(1 * 32 + d) * 36]) + bhhs[1 * 32 + d];
    float gh2_n = dot32(&h1s[rl][0], &whh[(2 * 32 + d) * 36]) + bhhs[2 * 32 + d];
    float r2 = sigm(gi2_r + gh2_r);
    float z2 = sigm(gi2_z + gh2_z);
    float n2 = tanhf(gi2_n + r2 * gh2_n);
    float h2 = (1.f - z2) * n2 + z2 * h1;
    out[row * 32 + d] = h2;
}

extern "C" void kernel_launch(void* const* d_in, const int* in_sizes, int n_in,
                              void* d_out, int out_size, void* d_ws, size_t ws_size,
                              hipStream_t stream) {
    const float* nodes = (const float*)d_in[0];
    const float* edges = (const float*)d_in[1];
    const float* mask  = (const float*)d_in[2];
    const float* W_agg = (const float*)d_in[3];
    const float* b_agg = (const float*)d_in[4];
    const float* w_ih  = (const float*)d_in[5];
    const float* w_hh  = (const float*)d_in[6];
    const float* b_ih  = (const float*)d_in[7];
    const float* b_hh  = (const float*)d_in[8];
    float* out = (float*)d_out;
    float* agg = (float*)d_ws;   // 3072*32*4 = 384 KB scratch

    agg_kernel<<<GRID_A, 512, 0, stream>>>(nodes, edges, mask, W_agg, b_agg, agg);
    gru_kernel<<<PAIRS / 8, 256, 0, stream>>>(nodes, agg, w_ih, w_hh, b_ih, b_hh, out);
}

// Round 3
// 196.049 us; speedup vs baseline: 4.2214x; 3.9997x over previous
//
#include <hip/hip_runtime.h>
#include <math.h>

#define BB 32
#define NN 96
#define DD 32
#define FF 16
#define NE (NN * NN)          // 9216 edges per batch
#define PAIRS (BB * NN)       // 3072 (b,i) pairs
#define PPB 6                 // pairs per block (96 % 6 == 0 -> same b within block)
#define GRID_A (PAIRS / PPB)  // 512 blocks

// ---------------------------------------------------------------------------
// Kernel A: fused  A=relu(edges@W+b) ; msg = A·nodes[j] ; agg = sum_j mask*msg
//
// Register-resident W (no 64KB LDS tile, no spill):
//   8 waves/block. Wave wv: t-chunk tq = wv&3 (owns t = 4*tq .. 4*tq+3),
//   edge parity eh = wv>>2 (edges e = eh, eh+2, ...).
//   Lane l owns k = l + 64*t  ->  q = l&31, p = 2t + (l>>5).
//   Per-lane register budget: Wreg[16][4]=64 (loop-invariant) + ev/nv prefetch
//   32 + acc 4 + aggacc 4 + bv 4 + misc ~= 115 VGPR. NO __launch_bounds__
//   occupancy arg (rounds 1-2: forced caps of 128/64 caused 0.6-1.5 GB of
//   scratch spill traffic -> 711-766us memory-bound).
// Mask==0 edges skipped exactly (mask is exactly 0.0/1.0).
// ---------------------------------------------------------------------------
__global__ __launch_bounds__(512)
void agg_kernel(const float* __restrict__ nodes, const float* __restrict__ edges,
                const float* __restrict__ mask, const float* __restrict__ W_agg,
                const float* __restrict__ b_agg, float* __restrict__ agg_out) {
    __shared__ __align__(16) float nodl[NN * DD];   // 12 KB
    __shared__ int jlist[NN];
    __shared__ int jcnt;
    __shared__ float aggl[DD];

    const int tid  = threadIdx.x;
    const int lane = tid & 63;
    const int wv   = tid >> 6;       // 0..7
    const int tq   = wv & 3;         // t-chunk: t = 4*tq + t2
    const int eh   = wv >> 2;        // edge parity (stride 2)
    const int t0   = tq * 4;
    const int pair0 = blockIdx.x * PPB;
    const int b  = pair0 / NN;
    const int i0 = pair0 % NN;

    // W into registers: Wreg[f][t2] = W_agg[f*1024 + lane + 64*(t0+t2)]
    // (coalesced; W is 64KB shared by all blocks -> L1/L2 hits)
    float Wreg[FF][4];
    #pragma unroll
    for (int f = 0; f < FF; ++f)
        #pragma unroll
        for (int t2 = 0; t2 < 4; ++t2)
            Wreg[f][t2] = W_agg[f * 1024 + lane + 64 * (t0 + t2)];
    float bv[4];
    #pragma unroll
    for (int t2 = 0; t2 < 4; ++t2) bv[t2] = b_agg[lane + 64 * (t0 + t2)];

    // stage nodes[b]: 768 float4
    for (int v = tid; v < 768; v += 512)
        ((float4*)nodl)[v] = ((const float4*)(nodes + b * NN * DD))[v];

    for (int pp = 0; pp < PPB; ++pp) {
        const int i = i0 + pp;
        __syncthreads();                 // protect jlist/aggl from prev iter
        if (tid == 0) jcnt = 0;
        if (tid < DD) aggl[tid] = 0.f;
        __syncthreads();
        // compact unmasked edge list (order irrelevant for the sum)
        if (tid < NN) {
            if (mask[b * NE + i * NN + tid] != 0.f) {
                int p = atomicAdd(&jcnt, 1);
                jlist[p] = tid;
            }
        }
        __syncthreads();
        const int cnt = jcnt;

        float aggacc[4] = {0.f, 0.f, 0.f, 0.f};
        const float* ebase = edges + ((size_t)b * NE + (size_t)i * NN) * FF;

        // software-pipelined edge loop (prefetch next edge's 16 features)
        int j_cur = -1;
        float4 ev0, ev1, ev2, ev3;
        if (eh < cnt) {
            j_cur = __builtin_amdgcn_readfirstlane(jlist[eh]);
            const float* ep = ebase + j_cur * FF;
            ev0 = ((const float4*)ep)[0]; ev1 = ((const float4*)ep)[1];
            ev2 = ((const float4*)ep)[2]; ev3 = ((const float4*)ep)[3];
        }
        for (int e = eh; e < cnt; e += 2) {
            // issue next edge's loads before using current (hide latency)
            int j_nxt = -1;
            float4 nv0, nv1, nv2, nv3;
            if (e + 2 < cnt) {
                j_nxt = __builtin_amdgcn_readfirstlane(jlist[e + 2]);
                const float* ep = ebase + j_nxt * FF;
                nv0 = ((const float4*)ep)[0]; nv1 = ((const float4*)ep)[1];
                nv2 = ((const float4*)ep)[2]; nv3 = ((const float4*)ep)[3];
            }
            float acc[4] = {bv[0], bv[1], bv[2], bv[3]};
            #pragma unroll
            for (int u = 0; u < 4; ++u) {
                const float4 ev = (u == 0) ? ev0 : (u == 1) ? ev1
                                : (u == 2) ? ev2 : ev3;
                #pragma unroll
                for (int f2 = 0; f2 < 4; ++f2) {
                    const float ef = (f2 == 0) ? ev.x : (f2 == 1) ? ev.y
                                   : (f2 == 2) ? ev.z : ev.w;
                    #pragma unroll
                    for (int t2 = 0; t2 < 4; ++t2)
                        acc[t2] = fmaf(ef, Wreg[4 * u + f2][t2], acc[t2]);
                }
            }
            // epilogue: relu, multiply by nodes[j][q], accumulate (lane-private)
            const float nv = nodl[j_cur * DD + (lane & 31)];
            #pragma unroll
            for (int t2 = 0; t2 < 4; ++t2)
                aggacc[t2] = fmaf(fmaxf(acc[t2], 0.f), nv, aggacc[t2]);
            j_cur = j_nxt;
            ev0 = nv0; ev1 = nv1; ev2 = nv2; ev3 = nv3;
        }
        // q-reduction: butterfly within each 32-lane half (p = 2t + half)
        #pragma unroll
        for (int off = 16; off >= 1; off >>= 1)
            #pragma unroll
            for (int t2 = 0; t2 < 4; ++t2)
                aggacc[t2] += __shfl_xor(aggacc[t2], off, 64);
        if ((lane & 31) == 0) {
            const int half = lane >> 5;
            #pragma unroll
            for (int t2 = 0; t2 < 4; ++t2)
                atomicAdd(&aggl[2 * (t0 + t2) + half], aggacc[t2]);
        }
        __syncthreads();
        if (tid < DD) agg_out[(size_t)(pair0 + pp) * DD + tid] = aggl[tid];
    }
}

// ---------------------------------------------------------------------------
// Kernel B: GRU combiner. h1 = cell(h=0, nodes); h2 = cell(h1, agg). Out = h2.
// thread = (row, d); 8 rows per 256-thread block; weights staged padded [96][36].
// ---------------------------------------------------------------------------
__device__ __forceinline__ float dot32(const float* __restrict__ x,
                                       const float* __restrict__ w) {
    float s = 0.f;
    #pragma unroll
    for (int u = 0; u < 8; ++u) {
        float4 a = *(const float4*)(x + 4 * u);
        float4 c = *(const float4*)(w + 4 * u);
        s = fmaf(a.x, c.x, fmaf(a.y, c.y, fmaf(a.z, c.z, fmaf(a.w, c.w, s))));
    }
    return s;
}
__device__ __forceinline__ float sigm(float x) { return 1.f / (1.f + expf(-x)); }

__global__ __launch_bounds__(256)
void gru_kernel(const float* __restrict__ nodes, const float* __restrict__ agg,
                const float* __restrict__ w_ih, const float* __restrict__ w_hh,
                const float* __restrict__ b_ih, const float* __restrict__ b_hh,
                float* __restrict__ out) {
    __shared__ __align__(16) float wih[96 * 36];
    __shared__ __align__(16) float whh[96 * 36];
    __shared__ float bihs[96], bhhs[96];
    __shared__ __align__(16) float xs[8][32], as_[8][32], h1s[8][32];

    const int tid = threadIdx.x;
    // stage weights with +4 row padding (16B-aligned rows, spread banks)
    for (int v = tid; v < 768; v += 256) {
        int row = v >> 3, c4 = v & 7;
        *(float4*)&wih[row * 36 + c4 * 4] = ((const float4*)w_ih)[v];
        *(float4*)&whh[row * 36 + c4 * 4] = ((const float4*)w_hh)[v];
    }
    if (tid < 96) { bihs[tid] = b_ih[tid]; bhhs[tid] = b_hh[tid]; }

    const int rl = tid >> 5, d = tid & 31;
    const int row = blockIdx.x * 8 + rl;
    xs[rl][d]  = nodes[row * 32 + d];
    as_[rl][d] = agg[row * 32 + d];
    __syncthreads();

    // cell 1: h = 0  ->  gh = b_hh exactly
    float gi_r = dot32(&xs[rl][0], &wih[(0 * 32 + d) * 36]) + bihs[0 * 32 + d];
    float gi_z = dot32(&xs[rl][0], &wih[(1 * 32 + d) * 36]) + bihs[1 * 32 + d];
    float gi_n = dot32(&xs[rl][0], &wih[(2 * 32 + d) * 36]) + bihs[2 * 32 + d];
    float r1 = sigm(gi_r + bhhs[0 * 32 + d]);
    float z1 = sigm(gi_z + bhhs[1 * 32 + d]);
    float n1 = tanhf(gi_n + r1 * bhhs[2 * 32 + d]);
    float h1 = (1.f - z1) * n1;
    h1s[rl][d] = h1;
    __syncthreads();

    // cell 2: x = agg, h = h1
    float gi2_r = dot32(&as_[rl][0], &wih[(0 * 32 + d) * 36]) + bihs[0 * 32 + d];
    float gi2_z = dot32(&as_[rl][0], &wih[(1 * 32 + d) * 36]) + bihs[1 * 32 + d];
    float gi2_n = dot32(&as_[rl][0], &wih[(2 * 32 + d) * 36]) + bihs[2 * 32 + d];
    float gh2_r = dot32(&h1s[rl][0], &whh[(0 * 32 + d) * 36]) + bhhs[0 * 32 + d];
    float gh2_z = dot32(&h1s[rl][0], &whh[(1 * 32 + d) * 36]) + bhhs[1 * 32 + d];
    float gh2_n = dot32(&h1s[rl][0], &whh[(2 * 32 + d) * 36]) + bhhs[2 * 32 + d];
    float r2 = sigm(gi2_r + gh2_r);
    float z2 = sigm(gi2_z + gh2_z);
    float n2 = tanhf(gi2_n + r2 * gh2_n);
    float h2 = (1.f - z2) * n2 + z2 * h1;
    out[row * 32 + d] = h2;
}

extern "C" void kernel_launch(void* const* d_in, const int* in_sizes, int n_in,
                              void* d_out, int out_size, void* d_ws, size_t ws_size,
                              hipStream_t stream) {
    const float* nodes = (const float*)d_in[0];
    const float* edges = (const float*)d_in[1];
    const float* mask  = (const float*)d_in[2];
    const float* W_agg = (const float*)d_in[3];
    const float* b_agg = (const float*)d_in[4];
    const float* w_ih  = (const float*)d_in[5];
    const float* w_hh  = (const float*)d_in[6];
    const float* b_ih  = (const float*)d_in[7];
    const float* b_hh  = (const float*)d_in[8];
    float* out = (float*)d_out;
    float* agg = (float*)d_ws;   // 3072*32*4 = 384 KB scratch

    agg_kernel<<<GRID_A, 512, 0, stream>>>(nodes, edges, mask, W_agg, b_agg, agg);
    gru_kernel<<<PAIRS / 8, 256, 0, stream>>>(nodes, agg, w_ih, w_hh, b_ih, b_hh, out);
}

// Round 4
// 157.960 us; speedup vs baseline: 5.2393x; 1.2411x over previous
//
#include <hip/hip_runtime.h>
#include <math.h>

#define BB 32
#define NN 96
#define DD 32
#define FF 16
#define NE (NN * NN)          // 9216 edges per batch
#define PAIRS (BB * NN)       // 3072 (b,i) pairs
#define PPB 6                 // pairs per block; 2 pairs processed concurrently
#define GRID_F (PAIRS / PPB)  // 512 blocks = 2/CU
#define EG 6                  // edges per inner group

// ---------------------------------------------------------------------------
// Fused kernel: per (b,i):  A=relu(edges@W+b); m = sum_j mask*A·nodes[j];
// then the 2-step GRU for the block's 6 rows (reusing W's LDS for GRU weights).
//
// Lane->k map (b128-friendly, single-register aggregate):
//   8 waves: psel = wv>>2 picks one of 2 concurrent pairs, tq = wv&3 picks the
//   k-chunk [256tq, 256tq+256). Lane l owns k = 256tq + 4l + c, c=0..3:
//     p = k>>5 = 8tq + (l>>3)  (constant per lane -> aggacc is ONE register)
//     q = k&31 = 4(l&7) + c    (float4 of nodes[j], 8-way broadcast read)
//   W read per f: ds_read_b128 at Wl[f*1024 + 256tq + 4l] - contiguous 16B/lane,
//   conflict-free. Compiler cannot sink ds_reads to global (round-3 failure:
//   register-resident W was rematerialized as per-iteration global reloads,
//   VGPR=68, VALUBusy 44%, 125us latency-bound).
//   Each wave owns p-range [8tq,8tq+8) exclusively -> no atomics on output.
// Mask==0 edges skipped exactly (mask is exactly 0.0/1.0).
// __launch_bounds__(512,2): empirical VGPR cap = 256/arg2 = 128 (rounds 1-2:
// arg2=2 -> 128, arg2=4 -> 64). Live set ~105 -> no spill, 2 blocks/CU.
// ---------------------------------------------------------------------------
__device__ __forceinline__ float dot32(const float* __restrict__ x,
                                       const float* __restrict__ w) {
    float s = 0.f;
    #pragma unroll
    for (int u = 0; u < 8; ++u) {
        float4 a = *(const float4*)(x + 4 * u);
        float4 c = *(const float4*)(w + 4 * u);
        s = fmaf(a.x, c.x, fmaf(a.y, c.y, fmaf(a.z, c.z, fmaf(a.w, c.w, s))));
    }
    return s;
}
__device__ __forceinline__ float sigm(float x) { return 1.f / (1.f + expf(-x)); }

__global__ __launch_bounds__(512, 2)
void mp_fused(const float* __restrict__ nodes, const float* __restrict__ edges,
              const float* __restrict__ mask, const float* __restrict__ W_agg,
              const float* __restrict__ b_agg,
              const float* __restrict__ w_ih, const float* __restrict__ w_hh,
              const float* __restrict__ b_ih, const float* __restrict__ b_hh,
              float* __restrict__ out) {
    __shared__ __align__(16) float Wl[FF * 1024];   // 64 KB; reused for GRU wts
    __shared__ __align__(16) float nodl[NN * DD];   // 12 KB
    __shared__ int jlist[2][NN];
    __shared__ int jcnt[2];
    __shared__ __align__(16) float aggv[PPB][DD];
    __shared__ __align__(16) float h1v[PPB][DD];
    __shared__ float bih_s[96], bhh_s[96];

    const int tid  = threadIdx.x;
    const int lane = tid & 63;
    const int wv   = tid >> 6;       // 0..7
    const int tq   = wv & 3;         // k-chunk
    const int psel = wv >> 2;        // which of 2 concurrent pairs
    const int pair0 = blockIdx.x * PPB;
    const int b  = pair0 / NN;
    const int i0 = pair0 % NN;
    const int l8 = lane & 7;         // q-chunk id
    const int lp = lane >> 3;        // p offset within chunk
    const int wbase = 256 * tq + 4 * lane;

    // stage W_agg (4096 float4) and nodes[b] (768 float4)
    for (int v = tid; v < 4096; v += 512)
        ((float4*)Wl)[v] = ((const float4*)W_agg)[v];
    for (int v = tid; v < 768; v += 512)
        ((float4*)nodl)[v] = ((const float4*)(nodes + b * NN * DD))[v];

    const float4 bvv = *(const float4*)(b_agg + wbase);

    for (int pr = 0; pr < 3; ++pr) {
        __syncthreads();             // prev round's jlist reads done (+staging)
        if (tid < 2) jcnt[tid] = 0;
        __syncthreads();
        // compact unmasked edges for the 2 pairs (order irrelevant to sum)
        if (tid < 2 * NN) {
            const int ps = tid / NN, col = tid % NN;
            const int ii = i0 + 2 * pr + ps;
            if (mask[(size_t)b * NE + (size_t)ii * NN + col] != 0.f) {
                int p = atomicAdd(&jcnt[ps], 1);
                jlist[ps][p] = col;
            }
        }
        __syncthreads();
        const int i = i0 + 2 * pr + psel;
        const int cnt = __builtin_amdgcn_readfirstlane(jcnt[psel]);
        const float4* ebase4 =
            (const float4*)(edges + ((size_t)b * NE + (size_t)i * NN) * FF);

        float aggacc = 0.f;
        for (int e0 = 0; e0 < cnt; e0 += EG) {
            int jj[EG];
            #pragma unroll
            for (int e = 0; e < EG; ++e) {
                int idx = e0 + e; if (idx > cnt - 1) idx = cnt - 1;
                jj[e] = __builtin_amdgcn_readfirstlane(jlist[psel][idx]);
            }
            float acc[EG][4];
            #pragma unroll
            for (int e = 0; e < EG; ++e) {
                acc[e][0] = bvv.x; acc[e][1] = bvv.y;
                acc[e][2] = bvv.z; acc[e][3] = bvv.w;
            }
            #pragma unroll
            for (int u = 0; u < 4; ++u) {
                float4 ev[EG];
                #pragma unroll
                for (int e = 0; e < EG; ++e) ev[e] = ebase4[jj[e] * 4 + u];
                #pragma unroll
                for (int f2 = 0; f2 < 4; ++f2) {
                    const float4 w4 =
                        *(const float4*)(Wl + (4 * u + f2) * 1024 + wbase);
                    #pragma unroll
                    for (int e = 0; e < EG; ++e) {
                        const float ef = (f2 == 0) ? ev[e].x : (f2 == 1) ? ev[e].y
                                       : (f2 == 2) ? ev[e].z : ev[e].w;
                        acc[e][0] = fmaf(ef, w4.x, acc[e][0]);
                        acc[e][1] = fmaf(ef, w4.y, acc[e][1]);
                        acc[e][2] = fmaf(ef, w4.z, acc[e][2]);
                        acc[e][3] = fmaf(ef, w4.w, acc[e][3]);
                    }
                }
            }
            // epilogue: relu * nodes[j][q-chunk], lane-private accumulate
            #pragma unroll
            for (int e = 0; e < EG; ++e) {
                if (e0 + e < cnt) {
                    const float4 x4 =
                        *(const float4*)(nodl + jj[e] * DD + 4 * l8);
                    aggacc = fmaf(fmaxf(acc[e][0], 0.f), x4.x, aggacc);
                    aggacc = fmaf(fmaxf(acc[e][1], 0.f), x4.y, aggacc);
                    aggacc = fmaf(fmaxf(acc[e][2], 0.f), x4.z, aggacc);
                    aggacc = fmaf(fmaxf(acc[e][3], 0.f), x4.w, aggacc);
                }
            }
        }
        // reduce the 8 q-chunks (lanes sharing lane>>3)
        aggacc += __shfl_xor(aggacc, 1, 64);
        aggacc += __shfl_xor(aggacc, 2, 64);
        aggacc += __shfl_xor(aggacc, 4, 64);
        if (l8 == 0) aggv[2 * pr + psel][8 * tq + lp] = aggacc;
    }

    // ---- GRU phase: reuse Wl region for w_ih/w_hh (padded stride 36) ----
    __syncthreads();
    float* wihL = Wl;                // 96*36 = 3456 floats
    float* whhL = Wl + 3456;
    for (int v = tid; v < 768; v += 512) {
        int row = v >> 3, c4 = v & 7;
        *(float4*)&wihL[row * 36 + c4 * 4] = ((const float4*)w_ih)[v];
        *(float4*)&whhL[row * 36 + c4 * 4] = ((const float4*)w_hh)[v];
    }
    if (tid < 96) { bih_s[tid] = b_ih[tid]; bhh_s[tid] = b_hh[tid]; }
    __syncthreads();

    if (tid < PPB * DD) {
        const int pp = tid >> 5, d = tid & 31;
        const float* x = nodl + (i0 + pp) * DD;
        // cell 1: h = 0 -> gh = b_hh exactly
        float gi_r = dot32(x, &wihL[(0 * 32 + d) * 36]) + bih_s[d];
        float gi_z = dot32(x, &wihL[(1 * 32 + d) * 36]) + bih_s[32 + d];
        float gi_n = dot32(x, &wihL[(2 * 32 + d) * 36]) + bih_s[64 + d];
        float r1 = sigm(gi_r + bhh_s[d]);
        float z1 = sigm(gi_z + bhh_s[32 + d]);
        float n1 = tanhf(gi_n + r1 * bhh_s[64 + d]);
        h1v[pp][d] = (1.f - z1) * n1;
    }
    __syncthreads();
    if (tid < PPB * DD) {
        const int pp = tid >> 5, d = tid & 31;
        const float* a  = &aggv[pp][0];
        const float* h1 = &h1v[pp][0];
        float gi_r = dot32(a, &wihL[(0 * 32 + d) * 36]) + bih_s[d];
        float gi_z = dot32(a, &wihL[(1 * 32 + d) * 36]) + bih_s[32 + d];
        float gi_n = dot32(a, &wihL[(2 * 32 + d) * 36]) + bih_s[64 + d];
        float gh_r = dot32(h1, &whhL[(0 * 32 + d) * 36]) + bhh_s[d];
        float gh_z = dot32(h1, &whhL[(1 * 32 + d) * 36]) + bhh_s[32 + d];
        float gh_n = dot32(h1, &whhL[(2 * 32 + d) * 36]) + bhh_s[64 + d];
        float r2 = sigm(gi_r + gh_r);
        float z2 = sigm(gi_z + gh_z);
        float n2 = tanhf(gi_n + r2 * gh_n);
        float h2 = (1.f - z2) * n2 + z2 * h1[d];
        out[(size_t)(pair0 + pp) * DD + d] = h2;
    }
}

extern "C" void kernel_launch(void* const* d_in, const int* in_sizes, int n_in,
                              void* d_out, int out_size, void* d_ws, size_t ws_size,
                              hipStream_t stream) {
    const float* nodes = (const float*)d_in[0];
    const float* edges = (const float*)d_in[1];
    const float* mask  = (const float*)d_in[2];
    const float* W_agg = (const float*)d_in[3];
    const float* b_agg = (const float*)d_in[4];
    const float* w_ih  = (const float*)d_in[5];
    const float* w_hh  = (const float*)d_in[6];
    const float* b_ih  = (const float*)d_in[7];
    const float* b_hh  = (const float*)d_in[8];
    float* out = (float*)d_out;

    mp_fused<<<GRID_F, 512, 0, stream>>>(nodes, edges, mask, W_agg, b_agg,
                                         w_ih, w_hh, b_ih, b_hh, out);
}